// Round 1
// baseline (941.598 us; speedup 1.0000x reference)
//
#include <hip/hip_runtime.h>
#include <stdint.h>

#define IN_SZ 128
#define HID 128
#define OUT_SZ 67
#define SEQ 512
#define BATCH 2048
#define BT 16
#define NTHR 512
#define KTOT (IN_SZ + HID)
#define KPAD 260   // bf16 elems per sChi row: dword stride 130 == 2 mod 32 -> conflict-free b64
#define KPADX 132  // bf16 elems per sCxlo row

typedef __attribute__((ext_vector_type(4))) float f32x4;
typedef __attribute__((ext_vector_type(8))) short s16x8;
typedef __attribute__((ext_vector_type(4))) short s16x4;

static __device__ __forceinline__ unsigned short f2bf(float f) {
  union { float f; uint32_t u; } c; c.f = f;
  uint32_t u = c.u;
  uint32_t r = u + 0x7FFFu + ((u >> 16) & 1u);  // RNE
  return (unsigned short)(r >> 16);
}
static __device__ __forceinline__ float bf2f(unsigned short h) {
  union { uint32_t u; float f; } c; c.u = ((uint32_t)h) << 16;
  return c.f;
}

// D(+)= A*B ; A,B are 8 bf16 (4 VGPRs), acc f32x4. Inline asm avoids
// builtin signature ambiguity (v8i16 vs v8bf16) across ROCm versions.
static __device__ __forceinline__ void mfma_acc(f32x4& c, s16x8 a, s16x8 b) {
  asm("v_mfma_f32_16x16x32_bf16 %0, %1, %2, %0" : "+v"(c) : "v"(a), "v"(b));
}

__global__ __launch_bounds__(NTHR, 2) void rnn_kernel(
    const float* __restrict__ x, const float* __restrict__ hidden,
    const float* __restrict__ mask, const float* __restrict__ Wi2h,
    const float* __restrict__ bi2h, const float* __restrict__ Wi2o,
    const float* __restrict__ bi2o, float* __restrict__ Y) {

  __shared__ unsigned short sChi[BT][KPAD];   // C = [x_t ; h] hi bf16, rows = batch col
  __shared__ unsigned short sCxlo[BT][KPADX]; // x lo residual bf16 (k 0..127)

  const int tid = threadIdx.x;
  const int wave = tid >> 6;    // 0..7 == i2h M-tile
  const int lane = tid & 63;
  const int g = lane >> 4;      // k-group
  const int n16 = lane & 15;    // A: row within tile / B: batch col / D: col
  const int b0 = blockIdx.x * BT;

  // ---- Wi2h A-fragments in registers, hi/lo split ----
  // fragment k-map: j<4 -> k = 4g+j ; j>=4 -> k = 16+4g+(j-4)  (split-K x32 layout)
  s16x8 wHi[8], wLo[8];
  {
    const float* wrow = Wi2h + (size_t)(16 * wave + n16) * KTOT;
#pragma unroll
    for (int kt = 0; kt < 8; ++kt) {
      s16x8 h8, l8;
#pragma unroll
      for (int j = 0; j < 8; ++j) {
        int k = 32 * kt + 4 * g + (j & 3) + ((j >> 2) << 4);
        float w = wrow[k];
        unsigned short hi = f2bf(w);
        h8[j] = (short)hi;
        l8[j] = (short)f2bf(w - bf2f(hi));
      }
      wHi[kt] = h8; wLo[kt] = l8;
    }
  }

  // ---- Wi2o A-fragments (single bf16), waves 0..4, zero-padded rows >= 67 ----
  s16x8 wO[4];
  if (wave < 5) {
    int m = 16 * wave + n16;
#pragma unroll
    for (int kt = 0; kt < 4; ++kt) {
      s16x8 o8;
#pragma unroll
      for (int j = 0; j < 8; ++j) {
        int k = 32 * kt + 4 * g + (j & 3) + ((j >> 2) << 4);
        float w = (m < OUT_SZ) ? Wi2o[(size_t)m * HID + k] : 0.f;
        o8[j] = (short)f2bf(w);
      }
      wO[kt] = o8;
    }
  }

  // ---- biases for this lane's D rows (m = 16*wave + 4g + r) ----
  float bh[4], bo[4];
#pragma unroll
  for (int r = 0; r < 4; ++r) {
    int m = 16 * wave + 4 * g + r;
    bh[r] = bi2h[m];
    bo[r] = (wave < 5 && m < OUT_SZ) ? bi2o[m] : 0.f;
  }

  // ---- stage x_0 (hi/lo) and h0 = hidden*mask (hi) ----
  {
    int i = tid >> 2, bq = tid & 3;
    const f32x4 xv = *(const f32x4*)(x + ((size_t)i * SEQ + 0) * BATCH + b0 + 4 * bq);
#pragma unroll
    for (int q = 0; q < 4; ++q) {
      float v = xv[q];
      unsigned short hi = f2bf(v);
      sChi[4 * bq + q][i] = hi;
      sCxlo[4 * bq + q][i] = f2bf(v - bf2f(hi));
    }
    const f32x4 hv = *(const f32x4*)(hidden + (size_t)i * BATCH + b0 + 4 * bq);
    const f32x4 mv = *(const f32x4*)(mask + (size_t)i * BATCH + b0 + 4 * bq);
#pragma unroll
    for (int q = 0; q < 4; ++q)
      sChi[4 * bq + q][IN_SZ + i] = f2bf(hv[q] * mv[q]);
  }
  __syncthreads();

  for (int t = 0; t < SEQ; ++t) {
    // prefetch x_{t+1} into registers (consumed after barrier A)
    f32x4 xv;
    const bool havex = (t + 1 < SEQ);
    const int i = tid >> 2, bq = tid & 3;
    if (havex)
      xv = *(const f32x4*)(x + ((size_t)i * SEQ + (t + 1)) * BATCH + b0 + 4 * bq);

    // ---- i2h: D[16x16] += Wi2h_tile * C ; 3-term hi/lo split ----
    f32x4 accA = {0.f, 0.f, 0.f, 0.f};
    f32x4 accB = {0.f, 0.f, 0.f, 0.f};
#pragma unroll
    for (int kt = 0; kt < 8; ++kt) {
      const unsigned short* p = &sChi[n16][32 * kt + 4 * g];
      s16x4 c0 = *(const s16x4*)p;
      s16x4 c1 = *(const s16x4*)(p + 16);
      s16x8 ch = __builtin_shufflevector(c0, c1, 0, 1, 2, 3, 4, 5, 6, 7);
      mfma_acc(accA, wHi[kt], ch);
      mfma_acc(accB, wLo[kt], ch);
      if (kt < 4) {  // x-lo correction (k < 128 only; h carried single-bf16)
        const unsigned short* q2 = &sCxlo[n16][32 * kt + 4 * g];
        s16x4 d0 = *(const s16x4*)q2;
        s16x4 d1 = *(const s16x4*)(q2 + 16);
        s16x8 cl = __builtin_shufflevector(d0, d1, 0, 1, 2, 3, 4, 5, 6, 7);
        mfma_acc(accB, wHi[kt], cl);
      }
    }
    asm volatile("s_nop 7\n\ts_nop 7");  // MFMA->VALU read hazard insurance
    __syncthreads();                     // A: all reads of sChi/sCxlo done

    // ---- h_new = tanh(acc + bh) ; write h (bf16) at k = 128+m ----
    {
      s16x4 hp;
#pragma unroll
      for (int r = 0; r < 4; ++r) {
        float pre = accA[r] + accB[r] + bh[r];
        float e = __expf(2.f * pre);
        float th = 1.f - 2.f / (e + 1.f);
        hp[r] = (short)f2bf(th);
      }
      *(s16x4*)&sChi[n16][IN_SZ + 16 * wave + 4 * g] = hp;
    }
    // ---- write x_{t+1} (hi/lo) ----
    if (havex) {
#pragma unroll
      for (int q = 0; q < 4; ++q) {
        float v = xv[q];
        unsigned short hi = f2bf(v);
        sChi[4 * bq + q][i] = hi;
        sCxlo[4 * bq + q][i] = f2bf(v - bf2f(hi));
      }
    }
    __syncthreads();  // B: h_new and x_{t+1} visible

    // ---- i2o: out = relu(Wi2o * h_new + bo) ; store Y[:, t, b0:b0+16] ----
    if (wave < 5) {
      f32x4 ao = {0.f, 0.f, 0.f, 0.f};
#pragma unroll
      for (int kt = 0; kt < 4; ++kt) {
        const unsigned short* p = &sChi[n16][IN_SZ + 32 * kt + 4 * g];
        s16x4 c0 = *(const s16x4*)p;
        s16x4 c1 = *(const s16x4*)(p + 16);
        s16x8 ch = __builtin_shufflevector(c0, c1, 0, 1, 2, 3, 4, 5, 6, 7);
        mfma_acc(ao, wO[kt], ch);
      }
      asm volatile("s_nop 7\n\ts_nop 7");
#pragma unroll
      for (int r = 0; r < 4; ++r) {
        int m = 16 * wave + 4 * g + r;
        if (m < OUT_SZ) {
          float o = fmaxf(ao[r] + bo[r], 0.f);
          Y[((size_t)m * SEQ + t) * BATCH + b0 + n16] = o;
        }
      }
    }
  }
}

extern "C" void kernel_launch(void* const* d_in, const int* in_sizes, int n_in,
                              void* d_out, int out_size, void* d_ws, size_t ws_size,
                              hipStream_t stream) {
  const float* x      = (const float*)d_in[0];
  const float* hidden = (const float*)d_in[1];
  const float* mask   = (const float*)d_in[2];
  const float* Wi2h   = (const float*)d_in[3];
  const float* bi2h   = (const float*)d_in[4];
  const float* Wi2o   = (const float*)d_in[5];
  const float* bi2o   = (const float*)d_in[6];
  float* Y = (float*)d_out;
  (void)in_sizes; (void)n_in; (void)out_size; (void)d_ws; (void)ws_size;
  rnn_kernel<<<dim3(BATCH / BT), dim3(NTHR), 0, stream>>>(
      x, hidden, mask, Wi2h, bi2h, Wi2o, bi2o, Y);
}

// Round 3
// 637.772 us; speedup vs baseline: 1.4764x; 1.4764x over previous
//
#include <hip/hip_runtime.h>
#include <stdint.h>

#define IN_SZ 128
#define HID 128
#define OUT_SZ 67
#define SEQ 512
#define BATCH 2048
#define BT 16
#define NTHR 512
#define KTOT (IN_SZ + HID)
#define KPAD 260   // bf16 elems per sChi row: dword stride 130 == 2 mod 32 -> conflict-free b64
#define KPADX 132  // bf16 elems per sCxlo row

typedef __attribute__((ext_vector_type(4))) float f32x4;
typedef __attribute__((ext_vector_type(8))) short s16x8;
typedef __attribute__((ext_vector_type(4))) short s16x4;
typedef __attribute__((ext_vector_type(8))) __bf16 bf16x8;

static __device__ __forceinline__ unsigned short f2bf(float f) {
  union { float f; uint32_t u; } c; c.f = f;
  uint32_t u = c.u;
  uint32_t r = u + 0x7FFFu + ((u >> 16) & 1u);  // RNE
  return (unsigned short)(r >> 16);
}
static __device__ __forceinline__ float bf2f(unsigned short h) {
  union { uint32_t u; float f; } c; c.u = ((uint32_t)h) << 16;
  return c.f;
}

// D += A*B via the real builtin: compiler models MFMA hazards/latency
// (the R2 inline-asm version could be sunk past its s_nop insurance).
static __device__ __forceinline__ void mfma16(f32x4& c, s16x8 a, s16x8 b) {
  c = __builtin_amdgcn_mfma_f32_16x16x32_bf16(
        __builtin_bit_cast(bf16x8, a), __builtin_bit_cast(bf16x8, b), c, 0, 0, 0);
}

// Workgroup barrier draining ONLY LDS ops (lgkmcnt), never vmcnt, so the
// async x prefetch / Y stores float across steps (avoids the §5 barrier-drain
// stall that __syncthreads() emits).
static __device__ __forceinline__ void sync_lds() {
  __builtin_amdgcn_sched_barrier(0);
  asm volatile("s_waitcnt lgkmcnt(0)\n\ts_barrier" ::: "memory");
  __builtin_amdgcn_sched_barrier(0);
}

__global__ __launch_bounds__(NTHR, 2) void rnn_kernel(
    const float* __restrict__ x, const float* __restrict__ hidden,
    const float* __restrict__ mask, const float* __restrict__ Wi2h,
    const float* __restrict__ bi2h, const float* __restrict__ Wi2o,
    const float* __restrict__ bi2o, float* __restrict__ Y) {

  // Double-buffered C = [x_t ; h_t]; one barrier/step. Invariant: in the
  // window between barrier t and t+1, all LDS reads hit buf[p^1] and all
  // writes hit buf[p] -> race-free.
  __shared__ unsigned short sChi[2][BT][KPAD];
  __shared__ unsigned short sCxlo[2][BT][KPADX];

  const int tid = threadIdx.x;
  const int wave = tid >> 6;    // 0..7 == i2h M-tile
  const int lane = tid & 63;
  const int g = lane >> 4;      // k-group
  const int n16 = lane & 15;    // A: row within tile / B: batch col / D: col
  const int b0 = blockIdx.x * BT;

  // ---- Wi2h A-fragments in registers, hi/lo split ----
  // fragment k-map: j<4 -> k = 32kt+4g+j ; j>=4 -> k = 32kt+16+4g+(j-4)
  s16x8 wHi[8], wLo[8];
  {
    const float* wrow = Wi2h + (size_t)(16 * wave + n16) * KTOT;
#pragma unroll
    for (int kt = 0; kt < 8; ++kt) {
      s16x8 h8, l8;
#pragma unroll
      for (int j = 0; j < 8; ++j) {
        int k = 32 * kt + 4 * g + (j & 3) + ((j >> 2) << 4);
        float w = wrow[k];
        unsigned short hi = f2bf(w);
        h8[j] = (short)hi;
        l8[j] = (short)f2bf(w - bf2f(hi));
      }
      wHi[kt] = h8; wLo[kt] = l8;
    }
  }

  // ---- Wi2o A-fragments (single bf16), waves 0..4, zero-padded rows >= 67 ----
  s16x8 wO[4];
  if (wave < 5) {
    int m = 16 * wave + n16;
#pragma unroll
    for (int kt = 0; kt < 4; ++kt) {
      s16x8 o8;
#pragma unroll
      for (int j = 0; j < 8; ++j) {
        int k = 32 * kt + 4 * g + (j & 3) + ((j >> 2) << 4);
        float w = (m < OUT_SZ) ? Wi2o[(size_t)m * HID + k] : 0.f;
        o8[j] = (short)f2bf(w);
      }
      wO[kt] = o8;
    }
  }

  // ---- biases for this lane's D rows (m = 16*wave + 4g + r) ----
  float bh[4], bo[4];
#pragma unroll
  for (int r = 0; r < 4; ++r) {
    int m = 16 * wave + 4 * g + r;
    bh[r] = bi2h[m];
    bo[r] = (wave < 5 && m < OUT_SZ) ? bi2o[m] : 0.f;
  }

  const int i = tid >> 2, bq = tid & 3;

  // ---- stage x_0 (hi/lo) and h0 = hidden*mask (hi) into buf 0 ----
  {
    const f32x4 xv = *(const f32x4*)(x + ((size_t)i * SEQ + 0) * BATCH + b0 + 4 * bq);
#pragma unroll
    for (int q = 0; q < 4; ++q) {
      float v = xv[q];
      unsigned short hi = f2bf(v);
      sChi[0][4 * bq + q][i] = hi;
      sCxlo[0][4 * bq + q][i] = f2bf(v - bf2f(hi));
    }
    const f32x4 hv = *(const f32x4*)(hidden + (size_t)i * BATCH + b0 + 4 * bq);
    const f32x4 mv = *(const f32x4*)(mask + (size_t)i * BATCH + b0 + 4 * bq);
#pragma unroll
    for (int q = 0; q < 4; ++q)
      sChi[0][4 * bq + q][IN_SZ + i] = f2bf(hv[q] * mv[q]);
  }
  sync_lds();

  // ---- 2-deep x prefetch: xcur holds x_{t+1}; xnext in flight for x_{t+2}
  f32x4 xcur;
  xcur = *(const f32x4*)(x + ((size_t)i * SEQ + 1) * BATCH + b0 + 4 * bq);

  int p = 0;
  for (int t = 0; t < SEQ; ++t) {
    f32x4 xnext;
    const bool havenext = (t + 2 < SEQ);
    if (havenext)
      xnext = *(const f32x4*)(x + ((size_t)i * SEQ + (t + 2)) * BATCH + b0 + 4 * bq);

    // ---- i2h: D[16x16] += Wi2h_tile * C(buf p) ; 3-term hi/lo split ----
    f32x4 accA = {0.f, 0.f, 0.f, 0.f};
    f32x4 accB = {0.f, 0.f, 0.f, 0.f};
    f32x4 accC = {0.f, 0.f, 0.f, 0.f};
#pragma unroll
    for (int kt = 0; kt < 8; ++kt) {
      const unsigned short* pp = &sChi[p][n16][32 * kt + 4 * g];
      s16x4 c0 = *(const s16x4*)pp;
      s16x4 c1 = *(const s16x4*)(pp + 16);
      s16x8 ch = __builtin_shufflevector(c0, c1, 0, 1, 2, 3, 4, 5, 6, 7);
      mfma16(accA, wHi[kt], ch);
      mfma16(accB, wLo[kt], ch);
      if (kt < 4) {  // x-lo correction (k < 128 only; h carried single-bf16)
        const unsigned short* q2 = &sCxlo[p][n16][32 * kt + 4 * g];
        s16x4 d0 = *(const s16x4*)q2;
        s16x4 d1 = *(const s16x4*)(q2 + 16);
        s16x8 cl = __builtin_shufflevector(d0, d1, 0, 1, 2, 3, 4, 5, 6, 7);
        mfma16(accC, wHi[kt], cl);
      }
    }

    // ---- h_new = tanh(acc + bh) ; write h (bf16) into buf p^1 at k=128+m ----
    {
      s16x4 hp;
#pragma unroll
      for (int r = 0; r < 4; ++r) {
        float pre = accA[r] + accB[r] + accC[r] + bh[r];
        float e = __expf(2.f * pre);
        float th = 1.f - 2.f / (e + 1.f);
        hp[r] = (short)f2bf(th);
      }
      *(s16x4*)&sChi[p ^ 1][n16][IN_SZ + 16 * wave + 4 * g] = hp;
    }
    // ---- write x_{t+1} (hi/lo) into buf p^1 ----
    if (t + 1 < SEQ) {
#pragma unroll
      for (int q = 0; q < 4; ++q) {
        float v = xcur[q];
        unsigned short hi = f2bf(v);
        sChi[p ^ 1][4 * bq + q][i] = hi;
        sCxlo[p ^ 1][4 * bq + q][i] = f2bf(v - bf2f(hi));
      }
    }
    sync_lds();  // h_t and x_{t+1} visible in buf p^1 (LDS-only drain)

    // ---- i2o: out = relu(Wi2o * h_t + bo) ; h_t read from buf p^1 ----
    if (wave < 5) {
      f32x4 ao = {0.f, 0.f, 0.f, 0.f};
#pragma unroll
      for (int kt = 0; kt < 4; ++kt) {
        const unsigned short* pp = &sChi[p ^ 1][n16][IN_SZ + 32 * kt + 4 * g];
        s16x4 c0 = *(const s16x4*)pp;
        s16x4 c1 = *(const s16x4*)(pp + 16);
        s16x8 ch = __builtin_shufflevector(c0, c1, 0, 1, 2, 3, 4, 5, 6, 7);
        mfma16(ao, wO[kt], ch);
      }
#pragma unroll
      for (int r = 0; r < 4; ++r) {
        int m = 16 * wave + 4 * g + r;
        if (m < OUT_SZ) {
          float o = fmaxf(ao[r] + bo[r], 0.f);
          Y[((size_t)m * SEQ + t) * BATCH + b0 + n16] = o;
        }
      }
    }

    xcur = xnext;
    p ^= 1;
  }
}

extern "C" void kernel_launch(void* const* d_in, const int* in_sizes, int n_in,
                              void* d_out, int out_size, void* d_ws, size_t ws_size,
                              hipStream_t stream) {
  const float* x      = (const float*)d_in[0];
  const float* hidden = (const float*)d_in[1];
  const float* mask   = (const float*)d_in[2];
  const float* Wi2h   = (const float*)d_in[3];
  const float* bi2h   = (const float*)d_in[4];
  const float* Wi2o   = (const float*)d_in[5];
  const float* bi2o   = (const float*)d_in[6];
  float* Y = (float*)d_out;
  (void)in_sizes; (void)n_in; (void)out_size; (void)d_ws; (void)ws_size;
  rnn_kernel<<<dim3(BATCH / BT), dim3(NTHR), 0, stream>>>(
      x, hidden, mask, Wi2h, bi2h, Wi2o, bi2o, Y);
}